// Round 1
// baseline (824.706 us; speedup 1.0000x reference)
//
#include <hip/hip_runtime.h>

#define NTOK   131072
#define KCODES 1024
#define DIM    64
#define TPB    64        // tokens per block in main kernel
#define TAU    2e-3f

// ws layout:
// [0,    4096) : counts, 1024 x u32
// [4096, 4104) : loss accumulator, double
// [4112, 8208) : wsq, 1024 x float

__global__ __launch_bounds__(256) void vq_wsq_kernel(const float* __restrict__ W,
                                                     float* __restrict__ wsq) {
    int c = blockIdx.x * 256 + threadIdx.x;
    const float4* row = reinterpret_cast<const float4*>(W + (size_t)c * DIM);
    float a0 = 0.f, a1 = 0.f, a2 = 0.f, a3 = 0.f;
#pragma unroll
    for (int i = 0; i < 16; ++i) {
        float4 v = row[i];
        a0 += v.x * v.x; a1 += v.y * v.y; a2 += v.z * v.z; a3 += v.w * v.w;
    }
    wsq[c] = (a0 + a1) + (a2 + a3);
}

__global__ __launch_bounds__(256) void vq_main_kernel(
    const float* __restrict__ X, const float* __restrict__ W,
    const float* __restrict__ wsq, float* __restrict__ out,
    unsigned int* __restrict__ counts, double* __restrict__ loss_acc)
{
    const int tid  = threadIdx.x;
    const int lane = tid & 63;
    const int wv   = tid >> 6;                 // wave id 0..3
    const int t    = blockIdx.x * TPB + lane;  // this lane's token

    // x row in registers
    float x[DIM];
    {
        const float4* xr = reinterpret_cast<const float4*>(X + (size_t)t * DIM);
#pragma unroll
        for (int i = 0; i < 16; ++i) {
            float4 v = xr[i];
            x[4*i+0] = v.x; x[4*i+1] = v.y; x[4*i+2] = v.z; x[4*i+3] = v.w;
        }
    }
    float xsq = 0.f;
#pragma unroll
    for (int d = 0; d < DIM; ++d) xsq += x[d] * x[d];

    // each wave scans a contiguous 256-code chunk; base is wave-uniform ->
    // readfirstlane so W/wsq loads become scalar (s_load) and overlap FMAs
    const int cbase = __builtin_amdgcn_readfirstlane(wv << 8);

    float b1 = 3.4e38f, b2 = 3.4e38f;
    int   i1 = 0,       i2 = 0;
#pragma unroll 4
    for (int c = 0; c < 256; ++c) {
        const int cc = cbase + c;
        const float4* wr = reinterpret_cast<const float4*>(W + (size_t)cc * DIM);
        float a0 = 0.f, a1 = 0.f, a2 = 0.f, a3 = 0.f;
#pragma unroll
        for (int i = 0; i < 16; ++i) {
            float4 w4 = wr[i];
            a0 += x[4*i+0] * w4.x;
            a1 += x[4*i+1] * w4.y;
            a2 += x[4*i+2] * w4.z;
            a3 += x[4*i+3] * w4.w;
        }
        float dot  = (a0 + a1) + (a2 + a3);
        float dist = wsq[cc] - 2.0f * dot;     // xsq omitted: constant per token
        if (dist < b1)      { b2 = b1; i2 = i1; b1 = dist; i1 = cc; }
        else if (dist < b2) { b2 = dist; i2 = cc; }
    }

    __shared__ float s_b1[TPB][4], s_b2[TPB][4];
    __shared__ int   s_i1[TPB][4], s_i2[TPB][4];
    __shared__ int   idx_s[TPB];
    s_b1[lane][wv] = b1; s_b2[lane][wv] = b2;
    s_i1[lane][wv] = i1; s_i2[lane][wv] = i2;
    __syncthreads();

    float lterm = 0.f;  // valid for tid < TPB
    if (tid < TPB) {
        float B1 = 3.4e38f, B2 = 3.4e38f; int I1 = 0, I2 = 0;
#pragma unroll
        for (int s = 0; s < 4; ++s) {
            float v1 = s_b1[tid][s]; int j1 = s_i1[tid][s];
            float v2 = s_b2[tid][s]; int j2 = s_i2[tid][s];
            if (v1 < B1 || (v1 == B1 && j1 < I1)) { B2 = B1; I2 = I1; B1 = v1; I1 = j1; }
            else if (v1 < B2 || (v1 == B2 && j1 < I2)) { B2 = v1; I2 = j1; }
            if (v2 < B1 || (v2 == B1 && j2 < I1)) { B2 = B1; I2 = I1; B1 = v2; I1 = j2; }
            else if (v2 < B2 || (v2 == B2 && j2 < I2)) { B2 = v2; I2 = j2; }
        }
        // near-tie: decide in fp64 on the exact metric ||x - w||^2
        double dq;
        if (B2 - B1 < TAU) {
            const float* w1 = W + (size_t)I1 * DIM;
            const float* w2 = W + (size_t)I2 * DIM;
            double d1 = 0.0, d2 = 0.0;
#pragma unroll
            for (int d = 0; d < DIM; ++d) {
                double e1 = (double)x[d] - (double)w1[d];
                double e2 = (double)x[d] - (double)w2[d];
                d1 += e1 * e1; d2 += e2 * e2;
            }
            if (d2 < d1 || (d2 == d1 && I2 < I1)) { I1 = I2; dq = d2; }
            else dq = d1;
        } else {
            dq = (double)(xsq + B1);
        }
        idx_s[tid] = I1;
        atomicAdd(&counts[I1], 1u);
        lterm = (float)dq;
    }
    // loss partial: threads 0..63 are exactly wave 0
    if (tid < 64) {
        float v = lterm;
#pragma unroll
        for (int off = 32; off >= 1; off >>= 1) v += __shfl_down(v, off, 64);
        if (tid == 0) atomicAdd(loss_acc, (double)v);
    }
    __syncthreads();

    // quantized: out[1 ..), coalesced lanes over d (scalar stores: base misaligned by 4B)
    {
        const size_t base_row = (size_t)blockIdx.x * TPB;
        for (int i = tid; i < TPB * DIM; i += 256) {
            int r = i >> 6, d = i & 63;
            out[1 + (base_row + r) * DIM + d] = W[(size_t)idx_s[r] * DIM + d];
        }
    }
    // encodings: out[8388610 ..), 256 threads span one 4KB row -> coalesced.
    // base is 8B-aligned only -> float2 stores.
    {
        float* enc = out + 2 + (size_t)NTOK * DIM;
        const size_t base_row = (size_t)blockIdx.x * TPB;
        const int c0 = tid * 4;
        for (int r = 0; r < TPB; ++r) {
            const int idx = idx_s[r];
            float2 v0, v1;
            v0.x = (c0 + 0 == idx) ? 1.f : 0.f;
            v0.y = (c0 + 1 == idx) ? 1.f : 0.f;
            v1.x = (c0 + 2 == idx) ? 1.f : 0.f;
            v1.y = (c0 + 3 == idx) ? 1.f : 0.f;
            float* p = enc + (base_row + r) * (size_t)KCODES + c0;
            reinterpret_cast<float2*>(p)[0] = v0;
            *reinterpret_cast<float2*>(p + 2) = v1;
        }
    }
}

__global__ __launch_bounds__(256) void vq_finalize_kernel(
    const unsigned int* __restrict__ counts, const double* __restrict__ loss_acc,
    float* __restrict__ out)
{
    int tid = threadIdx.x;
    float h = 0.f;
    for (int i = tid; i < KCODES; i += 256) {
        float p = (float)counts[i] * (1.0f / (float)NTOK);
        h += p * logf(p + 1e-10f);
    }
    __shared__ float red[4];
#pragma unroll
    for (int off = 32; off >= 1; off >>= 1) h += __shfl_down(h, off, 64);
    if ((tid & 63) == 0) red[tid >> 6] = h;
    __syncthreads();
    if (tid == 0) {
        float ht = red[0] + red[1] + red[2] + red[3];
        out[(size_t)NTOK * DIM + 1] = expf(-ht);                       // perplexity
        out[0] = 0.25f * (float)(loss_acc[0] / ((double)NTOK * DIM));  // loss
    }
}

extern "C" void kernel_launch(void* const* d_in, const int* in_sizes, int n_in,
                              void* d_out, int out_size, void* d_ws, size_t ws_size,
                              hipStream_t stream) {
    const float* X = (const float*)d_in[0];   // inputs [131072,64]
    const float* W = (const float*)d_in[1];   // embedding_w [1024,64]
    float* out = (float*)d_out;
    unsigned int* counts   = (unsigned int*)d_ws;
    double*       loss_acc = (double*)((char*)d_ws + 4096);
    float*        wsq      = (float*)((char*)d_ws + 4112);

    hipMemsetAsync(d_ws, 0, 4104, stream);  // counts + loss accumulator
    vq_wsq_kernel<<<KCODES / 256, 256, 0, stream>>>(W, wsq);
    vq_main_kernel<<<NTOK / TPB, 256, 0, stream>>>(X, W, wsq, out, counts, loss_acc);
    vq_finalize_kernel<<<1, 256, 0, stream>>>(counts, loss_acc, out);
}

// Round 3
// 475.965 us; speedup vs baseline: 1.7327x; 1.7327x over previous
//
#include <hip/hip_runtime.h>

#define NTOK     131072
#define KCODES   1024
#define DIM      64
#define TAU_S    2e-3f
#define FLAG_CAP 32768

typedef unsigned short ushort_t;
typedef unsigned int uint_t;
typedef __attribute__((ext_vector_type(8))) short short8;
typedef __attribute__((ext_vector_type(4))) float f32x4;
typedef __attribute__((ext_vector_type(2))) float nf32x2;   // native vec for NT stores

// ws layout (bytes):
//      0 : counts u32[1024]
//   4096 : loss double
//   4104 : flag_count u32
//   4112 : wsq float[1024]
//   8208 : Wh ushort[65536]
// 139280 : Wl ushort[65536]
// 270352 : flags int[4*FLAG_CAP]  {tok, oldidx, dq_bits, pad}

__device__ inline ushort_t f2bf(float f) {
    uint_t u = __float_as_uint(f);
    return (ushort_t)((u + 0x7FFFu + ((u >> 16) & 1u)) >> 16);
}
__device__ inline float bf2f(ushort_t h) { return __uint_as_float(((uint_t)h) << 16); }

__device__ inline void pack8(float4 p, float4 q, short8& h, short8& l) {
    float v[8] = {p.x, p.y, p.z, p.w, q.x, q.y, q.z, q.w};
#pragma unroll
    for (int j = 0; j < 8; ++j) {
        ushort_t hb = f2bf(v[j]);
        float hf = bf2f(hb);
        ushort_t lb = f2bf(v[j] - hf);
        h[j] = (short)hb;
        l[j] = (short)lb;
    }
}

// ---- prep: split W into bf16 hi/lo, compute wsq ----
__global__ __launch_bounds__(256) void vq_prep(const float* __restrict__ W,
                                               ushort_t* __restrict__ Wh,
                                               ushort_t* __restrict__ Wl,
                                               float* __restrict__ wsq) {
    int e = blockIdx.x * 256 + threadIdx.x;  // 65536 elements
    float w = W[e];
    ushort_t hb = f2bf(w);
    float hf = bf2f(hb);
    ushort_t lb = f2bf(w - hf);
    Wh[e] = hb; Wl[e] = lb;
    float sq = w * w;
#pragma unroll
    for (int off = 32; off >= 1; off >>= 1) sq += __shfl_xor(sq, off, 64);
    if ((threadIdx.x & 63) == 0) wsq[e >> 6] = sq;  // one wave == one row of 64
}

// ---- main: bf16-split MFMA distance scan + fused top-2 argmax + stores ----
__global__ __launch_bounds__(256) void vq_main(
    const float* __restrict__ X, const float* __restrict__ W,
    const ushort_t* __restrict__ Wh, const ushort_t* __restrict__ Wl,
    const float* __restrict__ wsq, float* __restrict__ out,
    uint_t* __restrict__ counts, double* __restrict__ loss_acc,
    uint_t* __restrict__ flag_cnt, int* __restrict__ flags)
{
    const int tid  = threadIdx.x;
    const int lane = tid & 63;
    const int wv   = tid >> 6;
    const int row  = lane & 15;   // A-fragment row (token within wave tile)
    const int ks   = lane >> 4;   // k-slice
    const int TB   = blockIdx.x * 64;
    const int WB   = TB + wv * 16;

    // A tile: 16 tokens x 64 dims -> bf16 hi/lo frags, reused for all codes
    const float* xr = X + (size_t)(WB + row) * DIM + ks * 8;
    float4 a0 = *(const float4*)(xr);
    float4 a1 = *(const float4*)(xr + 4);
    float4 a2 = *(const float4*)(xr + 32);
    float4 a3 = *(const float4*)(xr + 36);

    float xsq = a0.x*a0.x + a0.y*a0.y + a0.z*a0.z + a0.w*a0.w
              + a1.x*a1.x + a1.y*a1.y + a1.z*a1.z + a1.w*a1.w
              + a2.x*a2.x + a2.y*a2.y + a2.z*a2.z + a2.w*a2.w
              + a3.x*a3.x + a3.y*a3.y + a3.z*a3.z + a3.w*a3.w;
    xsq += __shfl_xor(xsq, 16, 64);
    xsq += __shfl_xor(xsq, 32, 64);   // now lane holds xsq of token row (lane&15)

    short8 xh0, xl0, xh1, xl1;
    pack8(a0, a1, xh0, xl0);
    pack8(a2, a3, xh1, xl1);

    __shared__ float s_xsq[4][16];
    __shared__ int   s_idx[64];
    if (lane < 16) s_xsq[wv][lane] = xsq;   // intra-wave LDS, no barrier needed

    // track s = dot - wsq/2 (maximize); dist = -2*s
    float m1[4], m2[4]; int i1[4];
#pragma unroll
    for (int r = 0; r < 4; ++r) { m1[r] = -3.4e38f; m2[r] = -3.4e38f; i1[r] = 0; }

#pragma unroll 2
    for (int cb = 0; cb < KCODES; cb += 16) {
        const int col = cb + row;
        const float wsqv = wsq[col];
        const ushort_t* whp = Wh + (size_t)col * DIM + ks * 8;
        const ushort_t* wlp = Wl + (size_t)col * DIM + ks * 8;
        short8 bh0 = *(const short8*)(whp);
        short8 bh1 = *(const short8*)(whp + 32);
        short8 bl0 = *(const short8*)(wlp);
        short8 bl1 = *(const short8*)(wlp + 32);
        f32x4 acc;
        const float c0 = -0.5f * wsqv;
        acc[0] = c0; acc[1] = c0; acc[2] = c0; acc[3] = c0;
        acc = __builtin_amdgcn_mfma_f32_16x16x32_bf16(xh0, bh0, acc, 0, 0, 0);
        acc = __builtin_amdgcn_mfma_f32_16x16x32_bf16(xh1, bh1, acc, 0, 0, 0);
        acc = __builtin_amdgcn_mfma_f32_16x16x32_bf16(xh0, bl0, acc, 0, 0, 0);
        acc = __builtin_amdgcn_mfma_f32_16x16x32_bf16(xh1, bl1, acc, 0, 0, 0);
        acc = __builtin_amdgcn_mfma_f32_16x16x32_bf16(xl0, bh0, acc, 0, 0, 0);
        acc = __builtin_amdgcn_mfma_f32_16x16x32_bf16(xl1, bh1, acc, 0, 0, 0);
#pragma unroll
        for (int r = 0; r < 4; ++r) {
            float v = acc[r];
            bool gt = v > m1[r];                         // strict: ties keep lower idx
            m2[r] = fmaxf(fminf(v, m1[r]), m2[r]);       // 2nd-max update
            i1[r] = gt ? col : i1[r];
            m1[r] = fmaxf(v, m1[r]);
        }
    }

    // merge across the 16 lanes sharing group g = lane>>4 (code residues)
#pragma unroll
    for (int mask = 1; mask <= 8; mask <<= 1) {
#pragma unroll
        for (int r = 0; r < 4; ++r) {
            float v1 = __shfl_xor(m1[r], mask, 64);
            int   j1 = __shfl_xor(i1[r], mask, 64);
            float v2 = __shfl_xor(m2[r], mask, 64);
            bool take = (v1 > m1[r]) || (v1 == m1[r] && j1 < i1[r]);
            m2[r] = take ? fmaxf(m1[r], v2) : fmaxf(v1, m2[r]);
            m1[r] = take ? v1 : m1[r];
            i1[r] = take ? j1 : i1[r];
        }
    }

    float lsum = 0.f;
    if ((lane & 15) == 0) {
        const int g = lane >> 4;
#pragma unroll
        for (int r = 0; r < 4; ++r) {
            const int trow = g * 4 + r;       // token row within wave tile
            const int t = WB + trow;
            s_idx[wv * 16 + trow] = i1[r];
            atomicAdd(&counts[i1[r]], 1u);
            float dq = s_xsq[wv][trow] - 2.f * m1[r];   // ||x - w_i1||^2 approx
            lsum += dq;
            if (m1[r] - m2[r] < TAU_S) {                // near-tie -> fp64 recheck
                uint_t pos = atomicAdd(flag_cnt, 1u);
                if (pos < FLAG_CAP) {
                    flags[4 * pos + 0] = t;
                    flags[4 * pos + 1] = i1[r];
                    flags[4 * pos + 2] = __float_as_int(dq);
                }
            }
        }
    }
    lsum += __shfl_xor(lsum, 16, 64);
    lsum += __shfl_xor(lsum, 32, 64);
    if (lane == 0) atomicAdd(loss_acc, (double)lsum);
    __syncthreads();

    // quantized rows (out[1..]) — NT scalar stores (base 4B-aligned only)
    for (int i = tid; i < 64 * DIM / 4; i += 256) {
        int r = i >> 4;
        int d4 = (i & 15) * 4;
        const float4 w4 = *(const float4*)(W + (size_t)s_idx[r] * DIM + d4);
        float* q = out + 1 + (size_t)(TB + r) * DIM + d4;
        __builtin_nontemporal_store(w4.x, q);
        __builtin_nontemporal_store(w4.y, q + 1);
        __builtin_nontemporal_store(w4.z, q + 2);
        __builtin_nontemporal_store(w4.w, q + 3);
    }
    // encodings (out[8388610..]) — 256 threads span one 4KB row, NT 8B stores
    float* enc = out + 2 + (size_t)NTOK * DIM + (size_t)TB * KCODES;
    const int c0 = tid * 4;
    for (int r = 0; r < 64; ++r) {
        const int idx = s_idx[r];
        nf32x2 v0 = {0.f, 0.f}, v1 = {0.f, 0.f};
        if ((idx >> 2) == tid) {
            if (idx & 2) { if (idx & 1) v1.y = 1.f; else v1.x = 1.f; }
            else         { if (idx & 1) v0.y = 1.f; else v0.x = 1.f; }
        }
        nf32x2* p = (nf32x2*)(enc + (size_t)r * KCODES + c0);
        __builtin_nontemporal_store(v0, p);
        __builtin_nontemporal_store(v1, p + 1);
    }
}

// ---- refine: fp64 full rescan of flagged (near-tie) tokens, patch outputs ----
__global__ __launch_bounds__(256) void vq_refine(
    const float* __restrict__ X, const float* __restrict__ W,
    float* __restrict__ out, uint_t* __restrict__ counts,
    double* __restrict__ loss_acc, const uint_t* __restrict__ flag_cnt,
    const int* __restrict__ flags)
{
    const int tid = threadIdx.x;
    const int lane = tid & 63;
    const int wv = tid >> 6;
    uint_t n = *flag_cnt; if (n > FLAG_CAP) n = FLAG_CAP;
    __shared__ float sx[DIM];
    __shared__ double sbest[4];
    __shared__ int sbi[4];
    for (uint_t e = blockIdx.x; e < n; e += gridDim.x) {
        const int t   = flags[4 * e + 0];
        const int old = flags[4 * e + 1];
        const float dq_old = __int_as_float(flags[4 * e + 2]);
        __syncthreads();
        if (tid < DIM) sx[tid] = X[(size_t)t * DIM + tid];
        __syncthreads();
        double best = 1e300; int bi = KCODES;
        for (int k = 0; k < 4; ++k) {
            const int c = tid * 4 + k;
            const float* wr = W + (size_t)c * DIM;
            double d = 0.0;
            for (int dd = 0; dd < DIM; ++dd) {
                double diff = (double)sx[dd] - (double)wr[dd];
                d += diff * diff;
            }
            if (d < best) { best = d; bi = c; }
        }
#pragma unroll
        for (int mask = 1; mask <= 32; mask <<= 1) {
            double db = __shfl_xor(best, mask, 64);
            int    ib = __shfl_xor(bi, mask, 64);
            if (db < best || (db == best && ib < bi)) { best = db; bi = ib; }
        }
        if (lane == 0) { sbest[wv] = best; sbi[wv] = bi; }
        __syncthreads();
        if (tid == 0) {
            for (int w = 1; w < 4; ++w)
                if (sbest[w] < best || (sbest[w] == best && sbi[w] < bi)) { best = sbest[w]; bi = sbi[w]; }
            atomicAdd(loss_acc, best - (double)dq_old);  // exact-ify loss term
            if (bi != old) {
                atomicSub(&counts[old], 1u);
                atomicAdd(&counts[bi], 1u);
                float* encp = out + 2 + (size_t)NTOK * DIM + (size_t)t * KCODES;
                encp[old] = 0.f; encp[bi] = 1.f;
                float* q = out + 1 + (size_t)t * DIM;
                for (int dd = 0; dd < DIM; ++dd) q[dd] = W[(size_t)bi * DIM + dd];
            }
        }
    }
}

__global__ __launch_bounds__(256) void vq_finalize(
    const uint_t* __restrict__ counts, const double* __restrict__ loss_acc,
    float* __restrict__ out)
{
    int tid = threadIdx.x;
    float h = 0.f;
    for (int i = tid; i < KCODES; i += 256) {
        float p = (float)counts[i] * (1.0f / (float)NTOK);
        h += p * logf(p + 1e-10f);
    }
    __shared__ float red[4];
#pragma unroll
    for (int off = 32; off >= 1; off >>= 1) h += __shfl_down(h, off, 64);
    if ((tid & 63) == 0) red[tid >> 6] = h;
    __syncthreads();
    if (tid == 0) {
        float ht = red[0] + red[1] + red[2] + red[3];
        out[(size_t)NTOK * DIM + 1] = expf(-ht);                        // perplexity
        out[0] = 0.25f * (float)(loss_acc[0] / ((double)NTOK * DIM));   // loss
    }
}

extern "C" void kernel_launch(void* const* d_in, const int* in_sizes, int n_in,
                              void* d_out, int out_size, void* d_ws, size_t ws_size,
                              hipStream_t stream) {
    const float* X = (const float*)d_in[0];
    const float* W = (const float*)d_in[1];
    float* out = (float*)d_out;
    uint_t*   counts   = (uint_t*)d_ws;
    double*   loss_acc = (double*)((char*)d_ws + 4096);
    uint_t*   flag_cnt = (uint_t*)((char*)d_ws + 4104);
    float*    wsq      = (float*)((char*)d_ws + 4112);
    ushort_t* Wh       = (ushort_t*)((char*)d_ws + 8208);
    ushort_t* Wl       = (ushort_t*)((char*)d_ws + 139280);
    int*      flags    = (int*)((char*)d_ws + 270352);

    (void)hipMemsetAsync(d_ws, 0, 4112, stream);  // counts + loss + flag_cnt
    vq_prep<<<KCODES * DIM / 256, 256, 0, stream>>>(W, Wh, Wl, wsq);
    vq_main<<<NTOK / 64, 256, 0, stream>>>(X, W, Wh, Wl, wsq, out,
                                           counts, loss_acc, flag_cnt, flags);
    vq_refine<<<256, 256, 0, stream>>>(X, W, out, counts, loss_acc, flag_cnt, flags);
    vq_finalize<<<1, 256, 0, stream>>>(counts, loss_acc, out);
}